// Round 11
// baseline (209.406 us; speedup 1.0000x reference)
//
#include <hip/hip_runtime.h>

// B=2, T=2048, D=1024, H=16, HD=64.
// Inputs f32 (x, rope, W_attn, W_proj), mask ignored (causal recomputed).
// Output f32. Internal tensors bf16 in workspace.
// Pipeline: prep -> gemm_qkv (fused rope/scatter/V-transpose) -> attn -> gemm_out.

typedef __bf16 bf16x8 __attribute__((ext_vector_type(8)));
typedef float f32x4 __attribute__((ext_vector_type(4)));

__device__ __forceinline__ float bf2f(unsigned short u) {
  unsigned int i = ((unsigned int)u) << 16;
  return __builtin_bit_cast(float, i);
}
__device__ __forceinline__ unsigned short f2bf(float f) {
  unsigned int i = __builtin_bit_cast(unsigned int, f);
  i += 0x7FFFu + ((i >> 16) & 1u);   // round-to-nearest-even
  return (unsigned short)(i >> 16);
}
__device__ __forceinline__ unsigned int pack2(float a, float b) {
  return (unsigned int)f2bf(a) | ((unsigned int)f2bf(b) << 16);
}
// hardware packed f32->bf16 (RNE), lo = a, hi = b
__device__ __forceinline__ unsigned int cvtpk(float a, float b) {
  unsigned int r;
  asm("v_cvt_pk_bf16_f32 %0, %1, %2" : "=v"(r) : "v"(a), "v"(b));
  return r;
}

// async global->LDS, 16B per lane (lds dest = wave base + lane*16)
__device__ __forceinline__ void gload_lds16(const unsigned short* g, unsigned short* l) {
  __builtin_amdgcn_global_load_lds(
      (const __attribute__((address_space(1))) void*)g,
      (__attribute__((address_space(3))) void*)l, 16, 0, 0);
}

// ---------------------------------------------------------------------------
// Fused prep: [0,2048) convert x ; [2048,2816) transpose Wa ; [2816,3072) Wp.
// ---------------------------------------------------------------------------
__global__ __launch_bounds__(256) void prep_kernel(
    const float* __restrict__ x, unsigned short* __restrict__ xb,
    const float* __restrict__ Wa, unsigned short* __restrict__ WaT,
    const float* __restrict__ Wp, unsigned short* __restrict__ WpT)
{
  __shared__ unsigned short tileT[64][72];   // [c][r], padded
  const int bid = blockIdx.x, tid = threadIdx.x;

  if (bid < 2048) {             // ---- convert x (8 elems/thread) ----
    int i = bid * 256 + tid;
    const float4 a0 = *reinterpret_cast<const float4*>(&x[(size_t)i * 8]);
    const float4 a1 = *reinterpret_cast<const float4*>(&x[(size_t)i * 8 + 4]);
    uint4 pk;
    pk.x = pack2(a0.x, a0.y);
    pk.y = pack2(a0.z, a0.w);
    pk.z = pack2(a1.x, a1.y);
    pk.w = pack2(a1.z, a1.w);
    *reinterpret_cast<uint4*>(&xb[(size_t)i * 8]) = pk;
    return;
  }
  const float* W;
  unsigned short* WT;
  int R, C, c0, r0;
  if (bid < 2816) {
    int tb = bid - 2048;        // Wa: 48 x 16 tiles
    W = Wa; WT = WaT; R = 1024; C = 3072;
    c0 = (tb % 48) * 64; r0 = (tb / 48) * 64;
  } else {
    int tb = bid - 2816;        // Wp: 16 x 16 tiles
    W = Wp; WT = WpT; R = 1024; C = 1024;
    c0 = (tb % 16) * 64; r0 = (tb / 16) * 64;
  }
  const int rr = tid >> 4, cc = (tid & 15) * 4;
#pragma unroll
  for (int it = 0; it < 4; ++it) {
    int gr = r0 + rr + it * 16;
    float4 v = *reinterpret_cast<const float4*>(&W[(size_t)gr * C + c0 + cc]);
    tileT[cc + 0][rr + it * 16] = f2bf(v.x);
    tileT[cc + 1][rr + it * 16] = f2bf(v.y);
    tileT[cc + 2][rr + it * 16] = f2bf(v.z);
    tileT[cc + 3][rr + it * 16] = f2bf(v.w);
  }
  __syncthreads();
  const int wc = tid >> 2, wk = (tid & 3) * 16;
  uint4 o0 = *reinterpret_cast<const uint4*>(&tileT[wc][wk]);
  uint4 o1 = *reinterpret_cast<const uint4*>(&tileT[wc][wk + 8]);
  unsigned short* dst = &WT[(size_t)(c0 + wc) * R + r0 + wk];
  *reinterpret_cast<uint4*>(dst) = o0;
  *reinterpret_cast<uint4*>(dst + 8) = o1;
}

// ---------------------------------------------------------------------------
// Fused QKV GEMM: qkv_tile = xb * WaT^T, then per-block (section-uniform):
//   sec 0/1 (q/k): rope applied in-epilogue, scatter to Qb/Kb (B,H,T,64)
//   sec 2   (v)  : transposed write to VT (B,H,64,T)
// 128x128 tile, BK=32, 4 waves, m97 K-loop. XCD-swizzled block mapping.
// ---------------------------------------------------------------------------
__global__ __launch_bounds__(256) void gemm_qkv_kernel(
    const unsigned short* __restrict__ A, const unsigned short* __restrict__ BT,
    const float* __restrict__ rope,
    unsigned short* __restrict__ Qb, unsigned short* __restrict__ Kb,
    unsigned short* __restrict__ VT, int M, int N, int K)
{
  __shared__ alignas(16) unsigned short smem[16896];
  unsigned short* As = smem;
  unsigned short* Bs = smem + 4096;

  const int tid = threadIdx.x;
  const int nbx = gridDim.x;
  const int nwg = nbx * gridDim.y;
  const int orig = blockIdx.y * nbx + blockIdx.x;
  const int wg = (orig & 7) * (nwg >> 3) + (orig >> 3);
  const int m0 = (wg / nbx) * 128, n0 = (wg % nbx) * 128;

  const int w = tid >> 6, lane = tid & 63;
  const int wr = (w >> 1) * 64, wc = (w & 1) * 64;
  const int g = lane >> 4, r = lane & 15;

  f32x4 acc[4][4];
#pragma unroll
  for (int i = 0; i < 4; ++i)
#pragma unroll
    for (int j = 0; j < 4; ++j)
      acc[i][j] = f32x4{0.f, 0.f, 0.f, 0.f};

  const int srow = w * 32 + (lane >> 2);
  const int sk = (lane & 3) << 3;
  const size_t a_base = (size_t)(m0 + srow) * K + sk;
  const size_t b_base = (size_t)(n0 + srow) * K + sk;
  unsigned short* lA = &As[w * 1024 + lane * 8];
  unsigned short* lB = &Bs[w * 1024 + lane * 8];
  const size_t rstep = (size_t)16 * K;

  for (int k0 = 0; k0 < K; k0 += 32) {
    __syncthreads();
    gload_lds16(&A[a_base + k0], lA);
    gload_lds16(&A[a_base + k0 + rstep], lA + 512);
    gload_lds16(&BT[b_base + k0], lB);
    gload_lds16(&BT[b_base + k0 + rstep], lB + 512);
    __syncthreads();

    bf16x8 af[4], bff[4];
#pragma unroll
    for (int i = 0; i < 4; ++i)
      af[i] = __builtin_bit_cast(bf16x8,
          *reinterpret_cast<const uint4*>(&As[(wr + i * 16 + r) * 32 + g * 8]));
#pragma unroll
    for (int j = 0; j < 4; ++j)
      bff[j] = __builtin_bit_cast(bf16x8,
          *reinterpret_cast<const uint4*>(&Bs[(wc + j * 16 + r) * 32 + g * 8]));
#pragma unroll
    for (int i = 0; i < 4; ++i)
#pragma unroll
      for (int j = 0; j < 4; ++j)
        acc[i][j] = __builtin_amdgcn_mfma_f32_16x16x32_bf16(af[i], bff[j], acc[i][j], 0, 0, 0);
  }

  // ---- bf16 LDS repack: ct[128][132] ----
  __syncthreads();
  unsigned short* ct = smem;
#pragma unroll
  for (int i = 0; i < 4; ++i)
#pragma unroll
    for (int j = 0; j < 4; ++j) {
      int row0 = wr + i * 16 + g * 4;
      int col  = wc + j * 16 + r;
      unsigned int w01 = cvtpk(acc[i][j][0], acc[i][j][1]);
      unsigned int w23 = cvtpk(acc[i][j][2], acc[i][j][3]);
      ct[(row0 + 0) * 132 + col] = (unsigned short)(w01 & 0xffffu);
      ct[(row0 + 1) * 132 + col] = (unsigned short)(w01 >> 16);
      ct[(row0 + 2) * 132 + col] = (unsigned short)(w23 & 0xffffu);
      ct[(row0 + 3) * 132 + col] = (unsigned short)(w23 >> 16);
    }
  __syncthreads();

  const int sec = n0 >> 10;     // 0=q 1=k 2=v (tile never spans sections)
  if (sec < 2) {
    unsigned short* dstp = (sec == 0) ? Qb : Kb;
    const int prow = tid >> 4, pcol = (tid & 15) * 8;
    const int h = ((n0 & 1023) + pcol) >> 6;
    const int hd = pcol & 63;
#pragma unroll
    for (int p = 0; p < 8; ++p) {
      int row = p * 16 + prow;
      int rowM = m0 + row;
      int bb = rowM >> 11, tt = rowM & 2047;
      uint4 v = *reinterpret_cast<const uint4*>(&ct[row * 132 + pcol]);
      float x0 = bf2f((unsigned short)(v.x & 0xffffu)), x1 = bf2f((unsigned short)(v.x >> 16));
      float x2 = bf2f((unsigned short)(v.y & 0xffffu)), x3 = bf2f((unsigned short)(v.y >> 16));
      float x4 = bf2f((unsigned short)(v.z & 0xffffu)), x5 = bf2f((unsigned short)(v.z >> 16));
      float x6 = bf2f((unsigned short)(v.w & 0xffffu)), x7 = bf2f((unsigned short)(v.w >> 16));
      float4 rc0 = *reinterpret_cast<const float4*>(&rope[(size_t)tt * 64 + hd]);
      float4 rc1 = *reinterpret_cast<const float4*>(&rope[(size_t)tt * 64 + hd + 4]);
      float y0 = x0 * rc0.x - x1 * rc0.y, y1 = x1 * rc0.x + x0 * rc0.y;
      float y2 = x2 * rc0.z - x3 * rc0.w, y3 = x3 * rc0.z + x2 * rc0.w;
      float y4 = x4 * rc1.x - x5 * rc1.y, y5 = x5 * rc1.x + x4 * rc1.y;
      float y6 = x6 * rc1.z - x7 * rc1.w, y7 = x7 * rc1.z + x6 * rc1.w;
      uint4 o{cvtpk(y0, y1), cvtpk(y2, y3), cvtpk(y4, y5), cvtpk(y6, y7)};
      *reinterpret_cast<uint4*>(&dstp[((size_t)(bb * 16 + h) * 2048 + tt) * 64 + hd]) = o;
    }
  } else {
    const int col = tid >> 1, tch = (tid & 1) * 64;
    const int h = ((n0 - 2048) >> 6) + (col >> 6);
    const int hd = col & 63;
    const int bb = m0 >> 11, tt0 = m0 & 2047;
    unsigned short* vdst = &VT[((size_t)(bb * 16 + h) * 64 + hd) * 2048 + tt0 + tch];
#pragma unroll
    for (int j = 0; j < 8; ++j) {
      int t = tch + j * 8;
      unsigned int o0 = (unsigned int)ct[(t + 0) * 132 + col] | ((unsigned int)ct[(t + 1) * 132 + col] << 16);
      unsigned int o1 = (unsigned int)ct[(t + 2) * 132 + col] | ((unsigned int)ct[(t + 3) * 132 + col] << 16);
      unsigned int o2 = (unsigned int)ct[(t + 4) * 132 + col] | ((unsigned int)ct[(t + 5) * 132 + col] << 16);
      unsigned int o3 = (unsigned int)ct[(t + 6) * 132 + col] | ((unsigned int)ct[(t + 7) * 132 + col] << 16);
      *reinterpret_cast<uint4*>(&vdst[j * 8]) = uint4{o0, o1, o2, o3};
    }
  }
}

// ---------------------------------------------------------------------------
// Output GEMM: out(MxN f32) = A(MxK bf16) * BT(NxK bf16)^T. m97 K-loop.
// f32 LDS-repack epilogue -> fully coalesced float4 row stores.
// ---------------------------------------------------------------------------
__global__ __launch_bounds__(256) void gemm_out_kernel(
    const unsigned short* __restrict__ A, const unsigned short* __restrict__ BT,
    float* __restrict__ Cp, int M, int N, int K)
{
  __shared__ alignas(16) char smemc[67584];   // K-loop: As/Bs ; epilogue: f32 [128][132]
  unsigned short* As = (unsigned short*)smemc;
  unsigned short* Bs = (unsigned short*)(smemc + 8192);

  const int tid = threadIdx.x;
  const int nbx = gridDim.x;
  const int nwg = nbx * gridDim.y;
  const int orig = blockIdx.y * nbx + blockIdx.x;
  const int wg = (orig & 7) * (nwg >> 3) + (orig >> 3);
  const int m0 = (wg / nbx) * 128, n0 = (wg % nbx) * 128;

  const int w = tid >> 6, lane = tid & 63;
  const int wr = (w >> 1) * 64, wc = (w & 1) * 64;
  const int g = lane >> 4, r = lane & 15;

  f32x4 acc[4][4];
#pragma unroll
  for (int i = 0; i < 4; ++i)
#pragma unroll
    for (int j = 0; j < 4; ++j)
      acc[i][j] = f32x4{0.f, 0.f, 0.f, 0.f};

  const int srow = w * 32 + (lane >> 2);
  const int sk = (lane & 3) << 3;
  const size_t a_base = (size_t)(m0 + srow) * K + sk;
  const size_t b_base = (size_t)(n0 + srow) * K + sk;
  unsigned short* lA = &As[w * 1024 + lane * 8];
  unsigned short* lB = &Bs[w * 1024 + lane * 8];
  const size_t rstep = (size_t)16 * K;

  for (int k0 = 0; k0 < K; k0 += 32) {
    __syncthreads();
    gload_lds16(&A[a_base + k0], lA);
    gload_lds16(&A[a_base + k0 + rstep], lA + 512);
    gload_lds16(&BT[b_base + k0], lB);
    gload_lds16(&BT[b_base + k0 + rstep], lB + 512);
    __syncthreads();

    bf16x8 af[4], bff[4];
#pragma unroll
    for (int i = 0; i < 4; ++i)
      af[i] = __builtin_bit_cast(bf16x8,
          *reinterpret_cast<const uint4*>(&As[(wr + i * 16 + r) * 32 + g * 8]));
#pragma unroll
    for (int j = 0; j < 4; ++j)
      bff[j] = __builtin_bit_cast(bf16x8,
          *reinterpret_cast<const uint4*>(&Bs[(wc + j * 16 + r) * 32 + g * 8]));
#pragma unroll
    for (int i = 0; i < 4; ++i)
#pragma unroll
      for (int j = 0; j < 4; ++j)
        acc[i][j] = __builtin_amdgcn_mfma_f32_16x16x32_bf16(af[i], bff[j], acc[i][j], 0, 0, 0);
  }

  // ---- f32 LDS repack -> coalesced stores ----
  __syncthreads();
  float* ct = (float*)smemc;    // [128][132]
#pragma unroll
  for (int i = 0; i < 4; ++i)
#pragma unroll
    for (int j = 0; j < 4; ++j)
#pragma unroll
      for (int reg = 0; reg < 4; ++reg)
        ct[(wr + i * 16 + g * 4 + reg) * 132 + wc + j * 16 + r] = acc[i][j][reg];
  __syncthreads();
  const int prow = tid >> 5, pcol = (tid & 31) * 4;   // 32 lanes cover a 512B row
#pragma unroll
  for (int p = 0; p < 16; ++p) {
    int row = p * 8 + prow;
    float4 v = *reinterpret_cast<const float4*>(&ct[row * 132 + pcol]);
    *reinterpret_cast<float4*>(&Cp[(size_t)(m0 + row) * N + n0 + pcol]) = v;
  }
}

// ---------------------------------------------------------------------------
// MFMA causal flash attention, 8 waves (512 thr), KBLK=128, double-buffered,
// swapped-operand QK^T; per-lane scalar softmax; shuffle P-exchange;
// T13 defer-max; cvt_pk packing. LPT block order (heavy tiles first).
// Q/K bf16 (B,H,T,64); VT bf16 (B,H,64,T); O bf16 (B,T,D).
// ---------------------------------------------------------------------------
__global__ __launch_bounds__(512, 4) void attn_mfma_kernel(
    const unsigned short* __restrict__ Q, const unsigned short* __restrict__ K,
    const unsigned short* __restrict__ VT, unsigned short* __restrict__ O)
{
  __shared__ unsigned short Ks[2][128 * 64];  // [key][d] swizzled, dbuf (32KB)
  __shared__ unsigned short Vs[2][64 * 128];  // [d][key] swizzled, dbuf (32KB)

  const int bx = blockIdx.x;
  const int tile = 15 - (bx >> 5);           // LPT: heaviest tiles dispatched first
  const int bh = bx & 31;
  const int b = bh >> 4, h = bh & 15;
  const size_t base = (size_t)bh * 2048 * 64;
  const unsigned short* VTb = VT + (size_t)bh * 64 * 2048;

  const int tid = threadIdx.x, w = tid >> 6, lane = tid & 63;
  const int g = lane >> 4, r = lane & 15;
  const int q0 = tile * 128;
  const int wrow0 = q0 + w * 16;             // wave's 16 q-rows

  // Q as B-operand: col = q-row = wrow0+r, k = d = kk*32+g*8+j
  bf16x8 qf[2];
#pragma unroll
  for (int kk = 0; kk < 2; ++kk)
    qf[kk] = __builtin_bit_cast(bf16x8, *reinterpret_cast<const uint4*>(
        &Q[base + (size_t)(wrow0 + r) * 64 + kk * 32 + g * 8]));

  float m = -1e30f, l = 0.f;                 // per-lane scalar (q-row r)
  f32x4 ov[4];                               // O^T: row d = df*16+g*4+reg, col q=r
#pragma unroll
  for (int df = 0; df < 4; ++df) ov[df] = f32x4{0.f, 0.f, 0.f, 0.f};

  // K staging: thread covers rows srowK, srowK+64 (16B of d each)
  const int srowK = tid >> 3, sc8 = (tid & 7) * 8;
  const unsigned short* Kg = &K[base + (size_t)srowK * 64 + sc8];
  const int sbK = srowK * 128 + ((sc8 * 2) ^ ((srowK & 7) << 4));
  // V staging: thread covers (d0, ck) and (d0+32, ck), 16B of keys each
  const int d0 = tid >> 4, ck = (tid & 15) * 8;
  const unsigned short* Vg = &VTb[(size_t)d0 * 2048 + ck];
  const int sbV = d0 * 256 + ((ck * 2) ^ ((d0 & 7) << 4));

  const float cs = 0.125f * 1.44269504f;
  const int nkt = tile + 1;                  // K-tiles of 128

  // P-exchange sources (key-bit remap; low-5-bit structure as verified)
  const int srcA = ((g & 1) << 5) | r;
  const int srcB = srcA | 16;
  const int hsel = g >> 1;

  // prologue: stage tile 0
  uint4 k0r = *reinterpret_cast<const uint4*>(Kg);
  uint4 k1r = *reinterpret_cast<const uint4*>(Kg + (size_t)64 * 64);
  uint4 v0r = *reinterpret_cast<const uint4*>(Vg);
  uint4 v1r = *reinterpret_cast<const uint4*>(Vg + (size_t)32 * 2048);
  *reinterpret_cast<uint4*>((char*)Ks[0] + sbK) = k0r;
  *reinterpret_cast<uint4*>((char*)Ks[0] + sbK + 8192) = k1r;
  *reinterpret_cast<uint4*>((char*)Vs[0] + sbV) = v0r;
  *reinterpret_cast<uint4*>((char*)Vs[0] + sbV + 8192) = v1r;
  __syncthreads();

  for (int c = 0; c < nkt; ++c) {
    const int kb = c * 128;
    const int cur = c & 1;
    const bool pfn = (c + 1 < nkt);
    if (pfn) {   // issue next-tile loads early
      k0r = *reinterpret_cast<const uint4*>(Kg + (size_t)(kb + 128) * 64);
      k1r = *reinterpret_cast<const uint4*>(Kg + (size_t)(kb + 192) * 64);
      v0r = *reinterpret_cast<const uint4*>(Vg + kb + 128);
      v1r = *reinterpret_cast<const uint4*>(Vg + (size_t)32 * 2048 + kb + 128);
    }

    if (kb <= wrow0 + 15) {
      // --- QK^T swapped: lane holds S[key=kb+cf*16+g*4+reg][q=wrow0+r]
      f32x4 s[8];
#pragma unroll
      for (int cf = 0; cf < 8; ++cf) s[cf] = f32x4{0.f, 0.f, 0.f, 0.f};
      __builtin_amdgcn_s_setprio(1);
#pragma unroll
      for (int kk = 0; kk < 2; ++kk) {
#pragma unroll
        for (int cf = 0; cf < 8; ++cf) {
          int row = cf * 16 + r;
          const char* p = (const char*)Ks[cur] + row * 128 + ((kk * 64 + g * 16) ^ ((r & 7) << 4));
          bf16x8 kf = __builtin_bit_cast(bf16x8, *reinterpret_cast<const uint4*>(p));
          s[cf] = __builtin_amdgcn_mfma_f32_16x16x32_bf16(kf, qf[kk], s[cf], 0, 0, 0);
        }
      }
      __builtin_amdgcn_s_setprio(0);

      // --- causal mask (diagonal region only): key > q-row -> -inf
      if (kb + 127 > wrow0) {
#pragma unroll
        for (int cf = 0; cf < 8; ++cf) {
          int keyb = kb + cf * 16 + g * 4;
#pragma unroll
          for (int reg = 0; reg < 4; ++reg)
            if (keyb + reg > wrow0 + r) s[cf][reg] = -1e30f;
        }
      }

      // --- online softmax with T13 defer-max (one reduce per 128 keys) ---
      float vmx = s[0][0];
#pragma unroll
      for (int cf = 0; cf < 8; ++cf)
#pragma unroll
        for (int reg = 0; reg < 4; ++reg)
          vmx = fmaxf(vmx, s[cf][reg]);
      vmx = fmaxf(vmx, __shfl_xor(vmx, 16));
      vmx = fmaxf(vmx, __shfl_xor(vmx, 32));
      float mo = m;
      float mn, al;
      if (__all((vmx - mo) * cs <= 4.0f)) {
        mn = mo; al = 1.0f;
      } else {
        mn = fmaxf(mo, vmx);
        al = __builtin_amdgcn_exp2f((mo - mn) * cs);
        m = mn;
#pragma unroll
        for (int df = 0; df < 4; ++df) ov[df] *= al;
      }
      float ps = 0.f;
#pragma unroll
      for (int cf = 0; cf < 8; ++cf)
#pragma unroll
        for (int reg = 0; reg < 4; ++reg) {
          float p = __builtin_amdgcn_exp2f((s[cf][reg] - mn) * cs);
          s[cf][reg] = p;
          ps += p;
        }
      l = l * al + ps;

      unsigned int pk[8][2];
#pragma unroll
      for (int cf = 0; cf < 8; ++cf) {
        pk[cf][0] = cvtpk(s[cf][0], s[cf][1]);
        pk[cf][1] = cvtpk(s[cf][2], s[cf][3]);
      }

      // --- exchange P into B-operand fragments + PV (kk = key-chunk of 32) ---
      __builtin_amdgcn_s_setprio(1);
#pragma unroll
      for (int kk = 0; kk < 4; ++kk) {
        unsigned int a0 = __shfl(pk[2 * kk][0], srcA), b0 = __shfl(pk[2 * kk + 1][0], srcA);
        unsigned int a1 = __shfl(pk[2 * kk][1], srcA), b1 = __shfl(pk[2 * kk + 1][1], srcA);
        unsigned int a2 = __shfl(pk[2 * kk][0], srcB), b2 = __shfl(pk[2 * kk + 1][0], srcB);
        unsigned int a3 = __shfl(pk[2 * kk][1], srcB), b3 = __shfl(pk[2 * kk + 1][1], srcB);
        uint4 pw{ hsel ? b0 : a0, hsel ? b1 : a1, hsel ? b2 : a2, hsel ? b3 : a3 };
        bf16x8 pf = __builtin_bit_cast(bf16x8, pw);
#pragma unroll
        for (int df = 0; df < 4; ++df) {
          int row = df * 16 + r;
          const char* p = (const char*)Vs[cur] + row * 256 + ((kk * 64 + g * 16) ^ ((r & 7) << 4));
          bf16x8 vf = __builtin_bit_cast(bf16x8, *reinterpret_cast<const uint4*>(p));
          ov[df] = __builtin_amdgcn_mfma_f32_16x16x32_bf16(vf, pf, ov[df], 0, 0, 0);
        }
      }
      __builtin_amdgcn_s_setprio(0);
    }

    if (pfn) {
      *reinterpret_cast<uint4*>((char*)Ks[cur ^ 1] + sbK) = k0r;
      *reinterpret_cast<uint4*>((char*)Ks[cur ^ 1] + sbK + 8192) = k1r;
      *reinterpret_cast<uint4*>((char*)Vs[cur ^ 1] + sbV) = v0r;
      *reinterpret_cast<uint4*>((char*)Vs[cur ^ 1] + sbV + 8192) = v1r;
    }
    __syncthreads();
  }

  // --- finalize: l summed across the 4 g-lanes of this q-row ---
  float ls = l;
  ls += __shfl_xor(ls, 16);
  ls += __shfl_xor(ls, 32);
  float inv = 1.f / ls;
  size_t orow = (size_t)(b * 2048 + wrow0 + r) * 1024 + h * 64 + g * 4;
#pragma unroll
  for (int df = 0; df < 4; ++df) {
    uint2 o;
    o.x = cvtpk(ov[df][0] * inv, ov[df][1] * inv);
    o.y = cvtpk(ov[df][2] * inv, ov[df][3] * inv);
    *reinterpret_cast<uint2*>(&O[orow + df * 16]) = o;
  }
}

// ---------------------------------------------------------------------------
extern "C" void kernel_launch(void* const* d_in, const int* in_sizes, int n_in,
                              void* d_out, int out_size, void* d_ws, size_t ws_size,
                              hipStream_t stream)
{
  (void)in_sizes; (void)n_in; (void)out_size; (void)ws_size;
  const float* x    = (const float*)d_in[0];   // (B,T,D) f32
  const float* rope = (const float*)d_in[1];   // (T,32,2) f32
  const float* Wa   = (const float*)d_in[2];   // (D,3D) f32
  const float* Wp   = (const float*)d_in[3];   // (D,D) f32
  // d_in[4] = causal mask (ignored; recomputed)

  unsigned short* ws  = (unsigned short*)d_ws;
  unsigned short* xb  = ws;
  unsigned short* WaT = xb  + (size_t)4096 * 1024;
  unsigned short* WpT = WaT + (size_t)1024 * 3072;
  unsigned short* Qb  = WpT + (size_t)1024 * 1024;
  unsigned short* Kb  = Qb  + (size_t)32 * 2048 * 64;
  unsigned short* VT  = Kb  + (size_t)32 * 2048 * 64;
  unsigned short* O   = VT  + (size_t)32 * 2048 * 64;
  float* out = (float*)d_out;

  prep_kernel<<<3072, 256, 0, stream>>>(x, xb, Wa, WaT, Wp, WpT);
  gemm_qkv_kernel<<<dim3(3072 / 128, 4096 / 128), 256, 0, stream>>>(
      xb, WaT, rope, Qb, Kb, VT, 4096, 3072, 1024);
  attn_mfma_kernel<<<512, 512, 0, stream>>>(Qb, Kb, VT, O);
  gemm_out_kernel<<<dim3(1024 / 128, 4096 / 128), 256, 0, stream>>>(
      O, WpT, out, 4096, 1024, 1024);
}